// Round 4
// baseline (163.302 us; speedup 1.0000x reference)
//
#include <hip/hip_runtime.h>

#define NN 4096
#define FIN 256
#define CC 256
#define NH 8

typedef __attribute__((ext_vector_type(8))) short short8;
typedef __attribute__((ext_vector_type(4))) float f32x4;
typedef __attribute__((ext_vector_type(4))) unsigned int u32x4;

__device__ __forceinline__ unsigned cvtpk_bf16(float lo, float hi) {
  unsigned r;
  asm("v_cvt_pk_bf16_f32 %0, %1, %2" : "=v"(r) : "v"(lo), "v"(hi));
  return r;
}

__device__ __forceinline__ unsigned short bf16rn(float x) {
  unsigned int u = __builtin_bit_cast(unsigned int, x);
  u += 0x7fffu + ((u >> 16) & 1u);
  return (unsigned short)(u >> 16);
}

// ---------------- K1: g = h@W, fused epilogue ----------------
// writes gT (bf16, [c=h*32+f][n]), spack[h][n]=(s_src, e^s, e^.2s, 0),
// dtrip[3][h][n] = (-s_dst, e^sd, e^{0.2 sd})
#define GROWS 8
__global__ __launch_bounds__(256) void k_gemm(
    const float* __restrict__ h, const float* __restrict__ W,
    const float* __restrict__ a, unsigned short* __restrict__ gT,
    float4* __restrict__ spack, float* __restrict__ dtrip) {
  __shared__ float hs[GROWS][FIN];
  const int r0 = blockIdx.x * GROWS;
  const int t = threadIdx.x;
#pragma unroll
  for (int idx = t; idx < GROWS * FIN / 4; idx += 256) {
    const int r = idx >> 6, c4 = idx & 63;
    *(float4*)&hs[r][c4 * 4] =
        *(const float4*)&h[(size_t)(r0 + r) * FIN + c4 * 4];
  }
  __syncthreads();
  const int c = t;
  float acc[GROWS];
#pragma unroll
  for (int r = 0; r < GROWS; ++r) acc[r] = 0.f;
  for (int k = 0; k < FIN; k += 4) {
    const float w0 = W[(size_t)(k + 0) * CC + c];
    const float w1 = W[(size_t)(k + 1) * CC + c];
    const float w2 = W[(size_t)(k + 2) * CC + c];
    const float w3 = W[(size_t)(k + 3) * CC + c];
#pragma unroll
    for (int r = 0; r < GROWS; ++r) {
      const float4 hv = *(const float4*)&hs[r][k];
      acc[r] += hv.x * w0 + hv.y * w1 + hv.z * w2 + hv.w * w3;
    }
  }
  const int f = c & 31, hh = c >> 5;
  const float aS = a[f], aD = a[32 + f];
  unsigned short gu[GROWS];
#pragma unroll
  for (int r = 0; r < GROWS; ++r) {
    float ps = acc[r] * aS, pd = acc[r] * aD;
#pragma unroll
    for (int m = 1; m < 32; m <<= 1) {
      ps += __shfl_xor(ps, m, 64);
      pd += __shfl_xor(pd, m, 64);
    }
    if (f == 0) {
      const int n = r0 + r;
      spack[(size_t)hh * NN + n] =
          make_float4(ps, __expf(ps), __expf(0.2f * ps), 0.f);
      dtrip[(size_t)hh * NN + n] = -pd;
      dtrip[(size_t)NH * NN + (size_t)hh * NN + n] = __expf(pd);
      dtrip[2 * (size_t)NH * NN + (size_t)hh * NN + n] = __expf(0.2f * pd);
    }
    gu[r] = bf16rn(acc[r]);
  }
  uint4 gv;
  gv.x = (unsigned)gu[0] | ((unsigned)gu[1] << 16);
  gv.y = (unsigned)gu[2] | ((unsigned)gu[3] << 16);
  gv.z = (unsigned)gu[4] | ((unsigned)gu[5] << 16);
  gv.w = (unsigned)gu[6] | ((unsigned)gu[7] << 16);
  *(uint4*)(gT + (size_t)c * NN + r0) = gv;
}

// ---------------- K2: barrier-free fused masked-softmax + MFMA PV ----------
// 256-thread blocks = 4 independent waves; wave w handles heads {2w, 2w+1}.
// No LDS, no __syncthreads. block = (ib, sp); sp = bx&(splits-1) -> XCD-pinned.
// A-frag lane l: i = it*16 + (l&15), k(=j) = 8*(l>>4)+e. l via ones-MFMA.
__global__ __launch_bounds__(256, 4) void k_attn(
    const int* __restrict__ adj, const unsigned short* __restrict__ gT,
    const float4* __restrict__ spack, const float* __restrict__ dtrip,
    float* __restrict__ acc_ws, float* __restrict__ l_ws,
    float* __restrict__ out, const int splits, const int direct) {
  const int lane = threadIdx.x & 63;
  const int w = threadIdx.x >> 6;
  const int il = lane & 15, q = lane >> 4;
  const int bx = blockIdx.x;
  const int sp = bx & (splits - 1);
  const int ib = bx / splits;
  const int i0 = ib * 32;
  const int jrange = NN / splits, j0b = sp * jrange;
  const int hbase = w * 2;

  // hoisted i-side scalars
  float ssv[2][2], e1v[2][2], e2v[2][2];
#pragma unroll
  for (int hp = 0; hp < 2; ++hp)
#pragma unroll
    for (int it = 0; it < 2; ++it) {
      const float4 v = spack[(size_t)(hbase + hp) * NN + i0 + it * 16 + il];
      ssv[hp][it] = v.x; e1v[hp][it] = v.y; e2v[hp][it] = v.z;
    }

  f32x4 acc[2][2][2];
  f32x4 lac[2][2];
#pragma unroll
  for (int hp = 0; hp < 2; ++hp)
#pragma unroll
    for (int it = 0; it < 2; ++it) {
#pragma unroll
      for (int r = 0; r < 4; ++r) lac[hp][it][r] = 0.f;
#pragma unroll
      for (int ft = 0; ft < 2; ++ft)
#pragma unroll
        for (int r = 0; r < 4; ++r) acc[hp][it][ft][r] = 0.f;
    }

  const short8 ones = {(short)0x3F80, (short)0x3F80, (short)0x3F80,
                       (short)0x3F80, (short)0x3F80, (short)0x3F80,
                       (short)0x3F80, (short)0x3F80};

  // hoisted row pointers
  const int* arow0 = adj + (size_t)(i0 + il) * NN;
  const int* arow1 = adj + (size_t)(i0 + 16 + il) * NN;
  const unsigned short* gr[2][2];
  const float* dnsd[2];
  const float* de1[2];
  const float* de2[2];
#pragma unroll
  for (int hp = 0; hp < 2; ++hp) {
    const int hh = hbase + hp;
    gr[hp][0] = gT + (size_t)(hh * 32 + il) * NN;
    gr[hp][1] = gT + (size_t)(hh * 32 + 16 + il) * NN;
    dnsd[hp] = dtrip + (size_t)hh * NN;
    de1[hp] = dtrip + (size_t)NH * NN + (size_t)hh * NN;
    de2[hp] = dtrip + 2 * (size_t)NH * NN + (size_t)hh * NN;
  }

  // register prefetch of the cold stream (adj): 4x int4 in flight (T14)
  int4 pa[4];
  auto issue = [&](int jq) {
    pa[0] = *(const int4*)&arow0[jq];
    pa[1] = *(const int4*)&arow0[jq + 4];
    pa[2] = *(const int4*)&arow1[jq];
    pa[3] = *(const int4*)&arow1[jq + 4];
  };
  issue(j0b + q * 8);

  const int nch = jrange / 32;
  for (int jc = 0; jc < nch; ++jc) {
    const int jq = j0b + jc * 32 + q * 8;
    // consume prefetched adj -> float multipliers (shared across both heads)
    float adf[2][8];
#pragma unroll
    for (int it = 0; it < 2; ++it) {
      const int4 a0 = pa[it * 2], a1 = pa[it * 2 + 1];
      adf[it][0] = (float)a0.x; adf[it][1] = (float)a0.y;
      adf[it][2] = (float)a0.z; adf[it][3] = (float)a0.w;
      adf[it][4] = (float)a1.x; adf[it][5] = (float)a1.y;
      adf[it][6] = (float)a1.z; adf[it][7] = (float)a1.w;
    }
    if (jc + 1 < nch) issue(jq + 32);  // overlap next chunk's adj with compute

#pragma unroll
    for (int hp = 0; hp < 2; ++hp) {
      float nsd[8], e1j[8], e2j[8];
      *(float4*)&nsd[0] = *(const float4*)&dnsd[hp][jq];
      *(float4*)&nsd[4] = *(const float4*)&dnsd[hp][jq + 4];
      *(float4*)&e1j[0] = *(const float4*)&de1[hp][jq];
      *(float4*)&e1j[4] = *(const float4*)&de1[hp][jq + 4];
      *(float4*)&e2j[0] = *(const float4*)&de2[hp][jq];
      *(float4*)&e2j[4] = *(const float4*)&de2[hp][jq + 4];
      const short8 b0 = *(const short8*)&gr[hp][0][jq];
      const short8 b1 = *(const short8*)&gr[hp][1][jq];
#pragma unroll
      for (int it = 0; it < 2; ++it) {
        const float ssl = ssv[hp][it];
        const float ei1 = e1v[hp][it], ei2 = e2v[hp][it];
        float wv[8];
#pragma unroll
        for (int e = 0; e < 8; ++e) {
          const bool pos = ssl > nsd[e];
          wv[e] = (pos ? ei1 : ei2) * (pos ? e1j[e] : e2j[e]) * adf[it][e];
        }
        u32x4 uu;
#pragma unroll
        for (int m = 0; m < 4; ++m) uu[m] = cvtpk_bf16(wv[2 * m], wv[2 * m + 1]);
        const short8 afr = __builtin_bit_cast(short8, uu);
        acc[hp][it][0] = __builtin_amdgcn_mfma_f32_16x16x32_bf16(
            afr, b0, acc[hp][it][0], 0, 0, 0);
        acc[hp][it][1] = __builtin_amdgcn_mfma_f32_16x16x32_bf16(
            afr, b1, acc[hp][it][1], 0, 0, 0);
        lac[hp][it] = __builtin_amdgcn_mfma_f32_16x16x32_bf16(
            afr, ones, lac[hp][it], 0, 0, 0);
      }
    }
  }

  if (direct) {
#pragma unroll
    for (int hp = 0; hp < 2; ++hp) {
      const int hh = hbase + hp;
#pragma unroll
      for (int it = 0; it < 2; ++it)
#pragma unroll
        for (int r = 0; r < 4; ++r) {
          const float inv = 1.f / lac[hp][it][r];
          const size_t irow = i0 + it * 16 + q * 4 + r;
#pragma unroll
          for (int ft = 0; ft < 2; ++ft)
            out[irow * CC + hh * 32 + ft * 16 + il] =
                acc[hp][it][ft][r] * inv;
        }
    }
  } else {
#pragma unroll
    for (int hp = 0; hp < 2; ++hp) {
      const int hh = hbase + hp;
#pragma unroll
      for (int it = 0; it < 2; ++it)
#pragma unroll
        for (int r = 0; r < 4; ++r) {
          const size_t irow = i0 + it * 16 + q * 4 + r;
          if (il == 0)
            l_ws[((size_t)sp * NH + hh) * NN + irow] = lac[hp][it][r];
#pragma unroll
          for (int ft = 0; ft < 2; ++ft)
            acc_ws[((size_t)sp * NN + irow) * CC + hh * 32 + ft * 16 + il] =
                acc[hp][it][ft][r];
        }
    }
  }
}

// ---------------- K3: combine split partials ----------------
__global__ __launch_bounds__(256) void k_combine(
    const float* __restrict__ acc_ws, const float* __restrict__ l_ws,
    float* __restrict__ out, const int splits) {
  const int idx = blockIdx.x * 256 + threadIdx.x;  // float4 index
  const int row = idx >> 6, c4 = idx & 63;
  const int hh = c4 >> 3;
  float ax = 0.f, ay = 0.f, az = 0.f, aw = 0.f, l = 0.f;
  for (int s = 0; s < splits; ++s) {
    const float4 v =
        *(const float4*)&acc_ws[((size_t)s * NN + row) * CC + c4 * 4];
    ax += v.x; ay += v.y; az += v.z; aw += v.w;
    l += l_ws[((size_t)s * NH + hh) * NN + row];
  }
  const float inv = 1.f / l;
  *(float4*)&out[(size_t)row * CC + c4 * 4] =
      make_float4(ax * inv, ay * inv, az * inv, aw * inv);
}

extern "C" void kernel_launch(void* const* d_in, const int* in_sizes, int n_in,
                              void* d_out, int out_size, void* d_ws,
                              size_t ws_size, hipStream_t stream) {
  (void)in_sizes; (void)n_in; (void)out_size;
  const float* h = (const float*)d_in[0];
  const int* adj = (const int*)d_in[1];
  const float* W = (const float*)d_in[2];
  const float* a = (const float*)d_in[3];
  float* out = (float*)d_out;
  char* ws = (char*)d_ws;

  unsigned short* gT = (unsigned short*)ws;               // 2 MB
  float4* spack = (float4*)(ws + (size_t)NN * CC * 2);    // 512 KB
  float* dtrip = (float*)(spack + (size_t)NH * NN);       // 384 KB
  char* after = (char*)(dtrip + 3 * (size_t)NH * NN);
  const size_t base = (size_t)(after - ws);
  const size_t per_split = (size_t)NN * CC * 4 + (size_t)NH * NN * 4;

  int splits = 1;
  if (ws_size >= base + 8 * per_split) splits = 8;
  else if (ws_size >= base + 4 * per_split) splits = 4;
  else if (ws_size >= base + 2 * per_split) splits = 2;

  k_gemm<<<NN / GROWS, 256, 0, stream>>>(h, W, a, gT, spack, dtrip);

  const int nblk = (NN / 32) * splits;
  if (splits == 1) {
    k_attn<<<nblk, 256, 0, stream>>>(adj, gT, spack, dtrip, nullptr, nullptr,
                                     out, 1, 1);
  } else {
    float* acc_ws = (float*)after;
    float* l_ws = acc_ws + (size_t)splits * NN * CC;
    k_attn<<<nblk, 256, 0, stream>>>(adj, gT, spack, dtrip, acc_ws, l_ws, out,
                                     splits, 0);
    k_combine<<<NN * CC / 4 / 256, 256, 0, stream>>>(acc_ws, l_ws, out,
                                                     splits);
  }
}

// Round 5
// 111.904 us; speedup vs baseline: 1.4593x; 1.4593x over previous
//
#include <hip/hip_runtime.h>

#define NN 4096
#define FIN 256
#define CC 256
#define NH 8

typedef __attribute__((ext_vector_type(8))) short short8;
typedef __attribute__((ext_vector_type(4))) float f32x4;
typedef __attribute__((ext_vector_type(4))) unsigned int u32x4;

__device__ __forceinline__ unsigned cvtpk_bf16(float lo, float hi) {
  unsigned r;
  asm("v_cvt_pk_bf16_f32 %0, %1, %2" : "=v"(r) : "v"(lo), "v"(hi));
  return r;
}

__device__ __forceinline__ unsigned short bf16rn(float x) {
  unsigned int u = __builtin_bit_cast(unsigned int, x);
  u += 0x7fffu + ((u >> 16) & 1u);
  return (unsigned short)(u >> 16);
}

// ---------------- K1: g = h@W, fused epilogue ----------------
// writes gT (bf16, [c=h*32+f][n]), spack[h][n]=(s_src, e^s, e^.2s, 0),
// dtrip blocked: [h][n>>3][3][8] = (-s_dst, e^sd, e^{0.2 sd}) per 8-node block
#define GROWS 8
__global__ __launch_bounds__(256) void k_gemm(
    const float* __restrict__ h, const float* __restrict__ W,
    const float* __restrict__ a, unsigned short* __restrict__ gT,
    float4* __restrict__ spack, float* __restrict__ dtrip) {
  __shared__ float hs[GROWS][FIN];
  const int r0 = blockIdx.x * GROWS;
  const int t = threadIdx.x;
#pragma unroll
  for (int idx = t; idx < GROWS * FIN / 4; idx += 256) {
    const int r = idx >> 6, c4 = idx & 63;
    *(float4*)&hs[r][c4 * 4] =
        *(const float4*)&h[(size_t)(r0 + r) * FIN + c4 * 4];
  }
  __syncthreads();
  const int c = t;
  float acc[GROWS];
#pragma unroll
  for (int r = 0; r < GROWS; ++r) acc[r] = 0.f;
  for (int k = 0; k < FIN; k += 4) {
    const float w0 = W[(size_t)(k + 0) * CC + c];
    const float w1 = W[(size_t)(k + 1) * CC + c];
    const float w2 = W[(size_t)(k + 2) * CC + c];
    const float w3 = W[(size_t)(k + 3) * CC + c];
#pragma unroll
    for (int r = 0; r < GROWS; ++r) {
      const float4 hv = *(const float4*)&hs[r][k];
      acc[r] += hv.x * w0 + hv.y * w1 + hv.z * w2 + hv.w * w3;
    }
  }
  const int f = c & 31, hh = c >> 5;
  const float aS = a[f], aD = a[32 + f];
  unsigned short gu[GROWS];
#pragma unroll
  for (int r = 0; r < GROWS; ++r) {
    float ps = acc[r] * aS, pd = acc[r] * aD;
#pragma unroll
    for (int m = 1; m < 32; m <<= 1) {
      ps += __shfl_xor(ps, m, 64);
      pd += __shfl_xor(pd, m, 64);
    }
    if (f == 0) {
      const int n = r0 + r;
      spack[(size_t)hh * NN + n] =
          make_float4(ps, __expf(ps), __expf(0.2f * ps), 0.f);
      const size_t db = ((size_t)hh * (NN / 8) + (n >> 3)) * 24 + (n & 7);
      dtrip[db] = -pd;
      dtrip[db + 8] = __expf(pd);
      dtrip[db + 16] = __expf(0.2f * pd);
    }
    gu[r] = bf16rn(acc[r]);
  }
  uint4 gv;
  gv.x = (unsigned)gu[0] | ((unsigned)gu[1] << 16);
  gv.y = (unsigned)gu[2] | ((unsigned)gu[3] << 16);
  gv.z = (unsigned)gu[4] | ((unsigned)gu[5] << 16);
  gv.w = (unsigned)gu[6] | ((unsigned)gu[7] << 16);
  *(uint4*)(gT + (size_t)c * NN + r0) = gv;
}

// ---------------- K2: barrier-free fused masked-softmax + MFMA PV ----------
// 256-thread blocks = 4 independent waves; wave w handles heads {2w, 2w+1}.
// No LDS, no __syncthreads. block = (ib, sp); sp = bx&(splits-1).
// A-frag lane l: i = it*16 + (l&15), k(=j) = 8*(l>>4)+e. l via ones-MFMA.
__global__ __launch_bounds__(256, 2) void k_attn(
    const int* __restrict__ adj, const unsigned short* __restrict__ gT,
    const float4* __restrict__ spack, const float* __restrict__ dtrip,
    float* __restrict__ acc_ws, float* __restrict__ l_ws,
    float* __restrict__ out, const int splits, const int direct) {
  const int lane = threadIdx.x & 63;
  const int w = threadIdx.x >> 6;
  const int il = lane & 15, q = lane >> 4;
  const int bx = blockIdx.x;
  const int sp = bx & (splits - 1);
  const int ib = bx / splits;
  const int i0 = ib * 32;
  const int jrange = NN / splits, j0b = sp * jrange;
  const int hbase = w * 2;

  // hoisted i-side scalars
  float ssv[2][2], e1v[2][2], e2v[2][2];
#pragma unroll
  for (int hp = 0; hp < 2; ++hp)
#pragma unroll
    for (int it = 0; it < 2; ++it) {
      const float4 v = spack[(size_t)(hbase + hp) * NN + i0 + it * 16 + il];
      ssv[hp][it] = v.x; e1v[hp][it] = v.y; e2v[hp][it] = v.z;
    }

  f32x4 acc[2][2][2];
  f32x4 lac[2][2];
#pragma unroll
  for (int hp = 0; hp < 2; ++hp)
#pragma unroll
    for (int it = 0; it < 2; ++it) {
#pragma unroll
      for (int r = 0; r < 4; ++r) lac[hp][it][r] = 0.f;
#pragma unroll
      for (int ft = 0; ft < 2; ++ft)
#pragma unroll
        for (int r = 0; r < 4; ++r) acc[hp][it][ft][r] = 0.f;
    }

  const short8 ones = {(short)0x3F80, (short)0x3F80, (short)0x3F80,
                       (short)0x3F80, (short)0x3F80, (short)0x3F80,
                       (short)0x3F80, (short)0x3F80};

  // hoisted row pointers
  const int* arow0 = adj + (size_t)(i0 + il) * NN;
  const int* arow1 = adj + (size_t)(i0 + 16 + il) * NN;
  const unsigned short* gr[2][2];
#pragma unroll
  for (int hp = 0; hp < 2; ++hp) {
    const int hh = hbase + hp;
    gr[hp][0] = gT + (size_t)(hh * 32 + il) * NN;
    gr[hp][1] = gT + (size_t)(hh * 32 + 16 + il) * NN;
  }
  // dtrip blocked base: this lane's 8-j block is (jq>>3) = (chunk base>>3)+q
  const float* dbase[2];
#pragma unroll
  for (int hp = 0; hp < 2; ++hp)
    dbase[hp] =
        dtrip + ((size_t)(hbase + hp) * (NN / 8) + (j0b >> 3) + q) * 24;

  // register prefetch of the cold stream (adj): 4x int4 in flight (T14)
  int4 pa[4];
  auto issue = [&](int jq) {
    pa[0] = *(const int4*)&arow0[jq];
    pa[1] = *(const int4*)&arow0[jq + 4];
    pa[2] = *(const int4*)&arow1[jq];
    pa[3] = *(const int4*)&arow1[jq + 4];
  };
  issue(j0b + q * 8);

  const int nch = jrange / 32;
  for (int jc = 0; jc < nch; ++jc) {
    const int jq = j0b + jc * 32 + q * 8;
    // consume prefetched adj -> float multipliers (shared across both heads)
    float adf[2][8];
#pragma unroll
    for (int it = 0; it < 2; ++it) {
      const int4 a0 = pa[it * 2], a1 = pa[it * 2 + 1];
      adf[it][0] = (float)a0.x; adf[it][1] = (float)a0.y;
      adf[it][2] = (float)a0.z; adf[it][3] = (float)a0.w;
      adf[it][4] = (float)a1.x; adf[it][5] = (float)a1.y;
      adf[it][6] = (float)a1.z; adf[it][7] = (float)a1.w;
    }
    if (jc + 1 < nch) issue(jq + 32);  // overlap next chunk's adj with compute

#pragma unroll
    for (int hp = 0; hp < 2; ++hp) {
      const float* dp = dbase[hp] + (size_t)jc * (4 * 24);  // 4 blocks/chunk
      float nsd[8], e1j[8], e2j[8];
      *(float4*)&nsd[0] = *(const float4*)(dp + 0);
      *(float4*)&nsd[4] = *(const float4*)(dp + 4);
      *(float4*)&e1j[0] = *(const float4*)(dp + 8);
      *(float4*)&e1j[4] = *(const float4*)(dp + 12);
      *(float4*)&e2j[0] = *(const float4*)(dp + 16);
      *(float4*)&e2j[4] = *(const float4*)(dp + 20);
      const short8 b0 = *(const short8*)&gr[hp][0][jq];
      const short8 b1 = *(const short8*)&gr[hp][1][jq];
#pragma unroll
      for (int it = 0; it < 2; ++it) {
        const float ssl = ssv[hp][it];
        const float ei1 = e1v[hp][it], ei2 = e2v[hp][it];
        float wv[8];
#pragma unroll
        for (int e = 0; e < 8; ++e) {
          const bool pos = ssl > nsd[e];
          wv[e] = (pos ? ei1 : ei2) * (pos ? e1j[e] : e2j[e]) * adf[it][e];
        }
        u32x4 uu;
#pragma unroll
        for (int m = 0; m < 4; ++m) uu[m] = cvtpk_bf16(wv[2 * m], wv[2 * m + 1]);
        const short8 afr = __builtin_bit_cast(short8, uu);
        acc[hp][it][0] = __builtin_amdgcn_mfma_f32_16x16x32_bf16(
            afr, b0, acc[hp][it][0], 0, 0, 0);
        acc[hp][it][1] = __builtin_amdgcn_mfma_f32_16x16x32_bf16(
            afr, b1, acc[hp][it][1], 0, 0, 0);
        lac[hp][it] = __builtin_amdgcn_mfma_f32_16x16x32_bf16(
            afr, ones, lac[hp][it], 0, 0, 0);
      }
    }
  }

  if (direct) {
#pragma unroll
    for (int hp = 0; hp < 2; ++hp) {
      const int hh = hbase + hp;
#pragma unroll
      for (int it = 0; it < 2; ++it)
#pragma unroll
        for (int r = 0; r < 4; ++r) {
          const float inv = 1.f / lac[hp][it][r];
          const size_t irow = i0 + it * 16 + q * 4 + r;
#pragma unroll
          for (int ft = 0; ft < 2; ++ft)
            out[irow * CC + hh * 32 + ft * 16 + il] =
                acc[hp][it][ft][r] * inv;
        }
    }
  } else {
#pragma unroll
    for (int hp = 0; hp < 2; ++hp) {
      const int hh = hbase + hp;
#pragma unroll
      for (int it = 0; it < 2; ++it)
#pragma unroll
        for (int r = 0; r < 4; ++r) {
          const size_t irow = i0 + it * 16 + q * 4 + r;
          if (il == 0)
            l_ws[((size_t)sp * NH + hh) * NN + irow] = lac[hp][it][r];
#pragma unroll
          for (int ft = 0; ft < 2; ++ft)
            acc_ws[((size_t)sp * NN + irow) * CC + hh * 32 + ft * 16 + il] =
                acc[hp][it][ft][r];
        }
    }
  }
}

// ---------------- K3: combine split partials ----------------
__global__ __launch_bounds__(256) void k_combine(
    const float* __restrict__ acc_ws, const float* __restrict__ l_ws,
    float* __restrict__ out, const int splits) {
  const int idx = blockIdx.x * 256 + threadIdx.x;  // float4 index
  const int row = idx >> 6, c4 = idx & 63;
  const int hh = c4 >> 3;
  float ax = 0.f, ay = 0.f, az = 0.f, aw = 0.f, l = 0.f;
  for (int s = 0; s < splits; ++s) {
    const float4 v =
        *(const float4*)&acc_ws[((size_t)s * NN + row) * CC + c4 * 4];
    ax += v.x; ay += v.y; az += v.z; aw += v.w;
    l += l_ws[((size_t)s * NH + hh) * NN + row];
  }
  const float inv = 1.f / l;
  *(float4*)&out[(size_t)row * CC + c4 * 4] =
      make_float4(ax * inv, ay * inv, az * inv, aw * inv);
}

extern "C" void kernel_launch(void* const* d_in, const int* in_sizes, int n_in,
                              void* d_out, int out_size, void* d_ws,
                              size_t ws_size, hipStream_t stream) {
  (void)in_sizes; (void)n_in; (void)out_size;
  const float* h = (const float*)d_in[0];
  const int* adj = (const int*)d_in[1];
  const float* W = (const float*)d_in[2];
  const float* a = (const float*)d_in[3];
  float* out = (float*)d_out;
  char* ws = (char*)d_ws;

  unsigned short* gT = (unsigned short*)ws;               // 2 MB
  float4* spack = (float4*)(ws + (size_t)NN * CC * 2);    // 512 KB
  float* dtrip = (float*)(spack + (size_t)NH * NN);       // 384 KB (blocked)
  char* after = (char*)(dtrip + (size_t)NH * (NN / 8) * 24);
  const size_t base = (size_t)(after - ws);
  const size_t per_split = (size_t)NN * CC * 4 + (size_t)NH * NN * 4;

  int splits = 1;
  if (ws_size >= base + 4 * per_split) splits = 4;
  else if (ws_size >= base + 2 * per_split) splits = 2;

  k_gemm<<<NN / GROWS, 256, 0, stream>>>(h, W, a, gT, spack, dtrip);

  const int nblk = (NN / 32) * splits;
  if (splits == 1) {
    k_attn<<<nblk, 256, 0, stream>>>(adj, gT, spack, dtrip, nullptr, nullptr,
                                     out, 1, 1);
  } else {
    float* acc_ws = (float*)after;
    float* l_ws = acc_ws + (size_t)splits * NN * CC;
    k_attn<<<nblk, 256, 0, stream>>>(adj, gT, spack, dtrip, acc_ws, l_ws, out,
                                     splits, 0);
    k_combine<<<NN * CC / 4 / 256, 256, 0, stream>>>(acc_ws, l_ws, out,
                                                     splits);
  }
}